// Round 3
// baseline (189.987 us; speedup 1.0000x reference)
//
#include <hip/hip_runtime.h>

#define IN_N   4096
#define OW     4084          // (4096 + 2*1 - 15) + 1
#define KS     15
#define XS     88            // LDS row stride (halfwords): 10 16B-units + pad; unit-stride 11 (odd)
#define XROWS  78            // 64 output rows + 14 halo
#define TILES  4             // stacked row-tiles per block (software pipeline)
#define NBX    64
#define NBY    16            // 16 groups x 4 tiles = 64 row-tiles

typedef __attribute__((ext_vector_type(8))) short     v8s;   // raw 16B
typedef __attribute__((ext_vector_type(8))) _Float16  v8h;   // f16 A/B frag (4 VGPR)
typedef __attribute__((ext_vector_type(4))) float     v4f;   // C/D frag
typedef __attribute__((ext_vector_type(2))) float     v2f;
typedef __attribute__((ext_vector_type(4))) unsigned  v4u;

// ---- pre-kernel: build the 15 banded-B MFMA fragments once into d_ws ----
// B_ky[k][n] = w[ky, k-1-n] (band k ∈ [n+1, n+15]); A k-window starts at even
// global col X0-2 (8B-aligned staging loads, 16B-aligned LDS rows).
// lane e holds B[k = (e>>4)*8 + j][n = e&15], j = 0..7  (16 B per lane)
__global__ void build_B(const float* __restrict__ w, unsigned short* __restrict__ Bg) {
    int ky = blockIdx.x;         // 15
    int e  = threadIdx.x;        // 64
    int n = e & 15, quad = e >> 4;
    unsigned short vals[8];
    #pragma unroll
    for (int j = 0; j < 8; ++j) {
        int d = quad * 8 + j - 1 - n;                 // shifted band
        _Float16 h = (_Float16)0.0f;
        if (d >= 0 && d < KS) h = (_Float16)w[ky * KS + d];
        union { _Float16 hh; unsigned short u; } cv; cv.hh = h;
        vals[j] = cv.u;
    }
    *(v8s*)(&Bg[(ky * 64 + e) * 8]) = *(const v8s*)vals;
}

__device__ __forceinline__ unsigned pk(float a, float b) {
    return __builtin_bit_cast(unsigned, __builtin_amdgcn_cvt_pkrtz(a, b));
}

__global__ __launch_bounds__(256, 4) void conv2d_mfma5(
    const float* __restrict__ x, const unsigned short* __restrict__ Bg,
    const float* __restrict__ bias, float* __restrict__ out)
{
    __shared__ unsigned short xtile[2][XROWS * XS] __attribute__((aligned(16)));

    const int tid = threadIdx.x;
    const int bx = blockIdx.x, by = blockIdx.y;
    const int X0  = bx * 64;
    const int RT0 = by * TILES;

    // staging map: 240 threads, u = 16B col-unit (0..9), r0 = row seed (0..23),
    // rows r0 + 24*i, i = 0..3 (i==3 only when r0 < 6) -> rows 0..77
    const int u  = tid % 10;
    const int r0 = tid / 10;
    const bool stager = (tid < 240);
    const bool colInt = (bx >= 1) & (bx <= 62);

    const int lane = tid & 63;
    const int wv   = tid >> 6;
    const int m    = lane & 15;
    const int quad = lane >> 4;
    const v8h* Bgv = (const v8h*)Bg;
    const float bv = bias[0];

    v2f L[4][4];   // held stage data (raw f32): 4 rows x 8 floats

    // -------- helpers --------
    auto load_int = [&](int R0) {            // issue next tile's loads into regs
        const float* xp = x + (size_t)(R0 - 1 + r0) * IN_N + (X0 - 2 + 8 * u);
        #pragma unroll
        for (int i = 0; i < 4; ++i) {
            if (i < 3 || r0 < 6) {
                const float* xr = xp + (size_t)(24 * i) * IN_N;
                #pragma unroll
                for (int j = 0; j < 4; ++j) L[i][j] = *(const v2f*)(xr + 2 * j);
            }
        }
    };
    auto write_int = [&](unsigned short* buf) {   // cvt + ds_write (late)
        #pragma unroll
        for (int i = 0; i < 4; ++i) {
            if (i < 3 || r0 < 6) {
                v4u p;
                p.x = pk(L[i][0].x, L[i][0].y);
                p.y = pk(L[i][1].x, L[i][1].y);
                p.z = pk(L[i][2].x, L[i][2].y);
                p.w = pk(L[i][3].x, L[i][3].y);
                *(v4u*)(buf + (r0 + 24 * i) * XS + 8 * u) = p;
            }
        }
    };
    auto stage_edge = [&](unsigned short* buf, int R0) {  // boundary tiles: direct
        if (!stager) return;
        const int gc0 = X0 - 2 + 8 * u;
        #pragma unroll
        for (int i = 0; i < 4; ++i) {
            int r = r0 + 24 * i;
            if (r < XROWS) {
                int gr = R0 - 1 + r;
                float f[8];
                #pragma unroll
                for (int j = 0; j < 8; ++j) f[j] = 0.0f;
                if ((unsigned)gr < (unsigned)IN_N) {
                    const float* xr = x + (size_t)gr * IN_N;
                    #pragma unroll
                    for (int j = 0; j < 8; ++j)
                        if ((unsigned)(gc0 + j) < (unsigned)IN_N) f[j] = xr[gc0 + j];
                }
                v4u p;
                p.x = pk(f[0], f[1]); p.y = pk(f[2], f[3]);
                p.z = pk(f[4], f[5]); p.w = pk(f[6], f[7]);
                *(v4u*)(buf + r * XS + 8 * u) = p;
            }
        }
    };

    // -------- prologue: stage tile 0 --------
    {
        const int RT = RT0;
        const bool tint = colInt & (RT >= 1) & (RT <= 62);
        if (tint) {
            if (stager) { load_int(RT * 64); write_int(&xtile[0][0]); }
        } else {
            stage_edge(&xtile[0][0], RT * 64);
        }
    }
    __syncthreads();

    // -------- pipelined tile loop --------
    for (int t = 0; t < TILES; ++t) {
        const unsigned short* cur = &xtile[t & 1][0];
        unsigned short* nxt = &xtile[(t + 1) & 1][0];
        const int RT = RT0 + t;
        const int R0 = RT * 64;
        const bool nxtExists = (t + 1 < TILES);
        const bool nint = colInt & ((RT + 1) <= 62);

        // 1) issue next tile's global loads (held in regs; no cvt yet)
        if (nxtExists & nint) { if (stager) load_int((RT + 1) * 64); }
        __builtin_amdgcn_sched_barrier(0);

        // 2) compute current tile from LDS
        v4f acc[4];
        #pragma unroll
        for (int c = 0; c < 4; ++c) acc[c] = (v4f){0.f, 0.f, 0.f, 0.f};

        const unsigned short* arow = cur + (wv * 16 + m) * XS + quad * 8;
        v8h bcur = Bgv[lane];
        v8h a0 = *(const v8h*)(arow + 0);
        v8h a1 = *(const v8h*)(arow + 16);
        v8h a2 = *(const v8h*)(arow + 32);
        v8h a3 = *(const v8h*)(arow + 48);

        #pragma unroll
        for (int ky = 0; ky < KS; ++ky) {
            const unsigned short* nrow = arow + XS;
            v8h bn = bcur, n0 = a0, n1 = a1, n2 = a2, n3 = a3;
            if (ky < KS - 1) {
                bn = Bgv[(ky + 1) * 64 + lane];
                n0 = *(const v8h*)(nrow + 0);
                n1 = *(const v8h*)(nrow + 16);
                n2 = *(const v8h*)(nrow + 32);
                n3 = *(const v8h*)(nrow + 48);
            }
            acc[0] = __builtin_amdgcn_mfma_f32_16x16x32_f16(a0, bcur, acc[0], 0, 0, 0);
            acc[1] = __builtin_amdgcn_mfma_f32_16x16x32_f16(a1, bcur, acc[1], 0, 0, 0);
            acc[2] = __builtin_amdgcn_mfma_f32_16x16x32_f16(a2, bcur, acc[2], 0, 0, 0);
            acc[3] = __builtin_amdgcn_mfma_f32_16x16x32_f16(a3, bcur, acc[3], 0, 0, 0);
            a0 = n0; a1 = n1; a2 = n2; a3 = n3; bcur = bn;
            arow = nrow;
        }

        // 3) store current tile
        const int orow0 = R0 + wv * 16 + quad * 4;
        const int ocol0 = X0 + m;
        if ((bx < NBX - 1) & (RT < 63)) {
            float* o0 = &out[(size_t)orow0 * OW + ocol0];
            #pragma unroll
            for (int c = 0; c < 4; ++c) {
                #pragma unroll
                for (int r = 0; r < 4; ++r)
                    o0[(size_t)r * OW + c * 16] = acc[c][r] + bv;
            }
        } else {
            #pragma unroll
            for (int c = 0; c < 4; ++c) {
                int oc = ocol0 + c * 16;
                if (oc < OW) {
                    #pragma unroll
                    for (int r = 0; r < 4; ++r) {
                        int orow = orow0 + r;
                        if (orow < OW)
                            out[(size_t)orow * OW + oc] = acc[c][r] + bv;
                    }
                }
            }
        }
        __builtin_amdgcn_sched_barrier(0);

        // 4) cvt + ds_write next tile into the other buffer
        if (nxtExists) {
            if (nint) { if (stager) write_int(nxt); }
            else      stage_edge(nxt, (RT + 1) * 64);
        }
        __syncthreads();
    }
}

extern "C" void kernel_launch(void* const* d_in, const int* in_sizes, int n_in,
                              void* d_out, int out_size, void* d_ws, size_t ws_size,
                              hipStream_t stream) {
    const float* x    = (const float*)d_in[0];
    const float* w    = (const float*)d_in[1];
    const float* bias = (const float*)d_in[2];
    float* out        = (float*)d_out;
    unsigned short* Bg = (unsigned short*)d_ws;     // 15 KiB of scratch

    build_B<<<dim3(KS), dim3(64), 0, stream>>>(w, Bg);
    dim3 grid(NBX, NBY);
    conv2d_mfma5<<<grid, dim3(256), 0, stream>>>(x, Bg, bias, out);
}

// Round 4
// 166.596 us; speedup vs baseline: 1.1404x; 1.1404x over previous
//
#include <hip/hip_runtime.h>

#define IN_N   4096
#define OW     4084          // (4096 + 2*1 - 15) + 1
#define KS     15
#define XS     280           // LDS row stride (halfwords): 140 dwords ≡ 12 mod 32 -> only 2-way (free) row aliasing
#define XROWS  30            // 16 output rows + 14 halo
#define XCOLS  272           // 34 x 16B units staged per row
#define NCG    16            // col groups of 256
#define NRT    256           // row tiles of 16

typedef __attribute__((ext_vector_type(8))) short     v8s;   // raw 16B
typedef __attribute__((ext_vector_type(8))) _Float16  v8h;   // f16 A/B frag (4 VGPR)
typedef __attribute__((ext_vector_type(4))) float     v4f;   // C/D frag
typedef __attribute__((ext_vector_type(2))) float     v2f;
typedef __attribute__((ext_vector_type(4))) unsigned  v4u;

// ---- pre-kernel: build the 15 banded-B MFMA fragments once into d_ws ----
// B_ky[k][n] = w[ky, k-1-n] (band k ∈ [n+1, n+15]); A k-window starts at even
// global col (base - 2)  -> 8B-aligned staging loads, 16B-aligned LDS rows.
// lane e holds B[k = (e>>4)*8 + j][n = e&15], j = 0..7  (16 B per lane)
__global__ void build_B(const float* __restrict__ w, unsigned short* __restrict__ Bg) {
    int ky = blockIdx.x;         // 15
    int e  = threadIdx.x;        // 64
    int n = e & 15, quad = e >> 4;
    unsigned short vals[8];
    #pragma unroll
    for (int j = 0; j < 8; ++j) {
        int d = quad * 8 + j - 1 - n;                 // shifted band
        _Float16 h = (_Float16)0.0f;
        if (d >= 0 && d < KS) h = (_Float16)w[ky * KS + d];
        union { _Float16 hh; unsigned short u; } cv; cv.hh = h;
        vals[j] = cv.u;
    }
    *(v8s*)(&Bg[(ky * 64 + e) * 8]) = *(const v8s*)vals;
}

__device__ __forceinline__ unsigned pk(float a, float b) {
    return __builtin_bit_cast(unsigned, __builtin_amdgcn_cvt_pkrtz(a, b));
}

// 16-row x 256-col tile per block: 4 waves side by side (64 cols each).
// Long horizontal HBM runs: reads 1088B/row, writes 1024B/row.
__global__ __launch_bounds__(256, 8) void conv2d_mfma6(
    const float* __restrict__ x, const unsigned short* __restrict__ Bg,
    const float* __restrict__ bias, float* __restrict__ out)
{
    __shared__ unsigned short xtile[XROWS * XS] __attribute__((aligned(16)));

    const int tid = threadIdx.x;
    const int cg = blockIdx.x;                 // 0..15 (fastest -> col-neighbors concurrent)
    const int rt = blockIdx.y;                 // 0..255
    const int X0 = cg * 256;
    const int R0 = rt * 16;

    const bool interior = (cg >= 1) & (cg <= 14) & (rt >= 1) & (rt <= 254);

    // ---- stage 30 x 272 cols fp32 -> f16 ----
    // 1020 16B-units: i = s*256 + tid, row = i/34, u = i%34
    if (interior) {
        #pragma unroll
        for (int s = 0; s < 4; ++s) {
            int i = s * 256 + tid;
            if (i < XROWS * 34) {
                int row = i / 34;
                int u   = i - 34 * row;
                const float* xr = x + (size_t)(R0 - 1 + row) * IN_N + (X0 - 2 + 8 * u);
                v2f f0 = *(const v2f*)(xr + 0);
                v2f f1 = *(const v2f*)(xr + 2);
                v2f f2 = *(const v2f*)(xr + 4);
                v2f f3 = *(const v2f*)(xr + 6);
                v4u p;
                p.x = pk(f0.x, f0.y);
                p.y = pk(f1.x, f1.y);
                p.z = pk(f2.x, f2.y);
                p.w = pk(f3.x, f3.y);
                *(v4u*)(&xtile[row * XS + 8 * u]) = p;     // ds_write_b128
            }
        }
    } else {
        #pragma unroll
        for (int s = 0; s < 4; ++s) {
            int i = s * 256 + tid;
            if (i < XROWS * 34) {
                int row = i / 34;
                int u   = i - 34 * row;
                int gr  = R0 - 1 + row;
                int gc0 = X0 - 2 + 8 * u;
                float f[8];
                #pragma unroll
                for (int j = 0; j < 8; ++j) f[j] = 0.0f;
                if ((unsigned)gr < (unsigned)IN_N) {
                    const float* xr = x + (size_t)gr * IN_N;
                    #pragma unroll
                    for (int j = 0; j < 8; ++j)
                        if ((unsigned)(gc0 + j) < (unsigned)IN_N) f[j] = xr[gc0 + j];
                }
                v4u p;
                p.x = pk(f[0], f[1]); p.y = pk(f[2], f[3]);
                p.z = pk(f[4], f[5]); p.w = pk(f[6], f[7]);
                *(v4u*)(&xtile[row * XS + 8 * u]) = p;
            }
        }
    }
    __syncthreads();

    // ---- MFMA main loop (identical structure to R1; col base per wave) ----
    const int lane = tid & 63;
    const int wv   = tid >> 6;                 // wave owns cols [64wv, 64wv+64)
    const int m    = lane & 15;
    const int quad = lane >> 4;

    v4f acc[4];
    #pragma unroll
    for (int t = 0; t < 4; ++t) acc[t] = (v4f){0.f, 0.f, 0.f, 0.f};

    const v8h* Bgv = (const v8h*)Bg;
    const unsigned short* arow = &xtile[m * XS + 64 * wv + quad * 8];

    v8h bcur = Bgv[lane];                      // ky = 0 (L2-resident)
    v8h a0 = *(const v8h*)(arow + 0);
    v8h a1 = *(const v8h*)(arow + 16);
    v8h a2 = *(const v8h*)(arow + 32);
    v8h a3 = *(const v8h*)(arow + 48);

    #pragma unroll
    for (int ky = 0; ky < KS; ++ky) {
        const unsigned short* nrow = arow + XS;
        v8h bn = bcur, n0 = a0, n1 = a1, n2 = a2, n3 = a3;
        if (ky < KS - 1) {
            bn = Bgv[(ky + 1) * 64 + lane];
            n0 = *(const v8h*)(nrow + 0);
            n1 = *(const v8h*)(nrow + 16);
            n2 = *(const v8h*)(nrow + 32);
            n3 = *(const v8h*)(nrow + 48);
        }
        acc[0] = __builtin_amdgcn_mfma_f32_16x16x32_f16(a0, bcur, acc[0], 0, 0, 0);
        acc[1] = __builtin_amdgcn_mfma_f32_16x16x32_f16(a1, bcur, acc[1], 0, 0, 0);
        acc[2] = __builtin_amdgcn_mfma_f32_16x16x32_f16(a2, bcur, acc[2], 0, 0, 0);
        acc[3] = __builtin_amdgcn_mfma_f32_16x16x32_f16(a3, bcur, acc[3], 0, 0, 0);
        a0 = n0; a1 = n1; a2 = n2; a3 = n3; bcur = bn;
        arow = nrow;
    }

    // ---- epilogue: out row = R0 + quad*4 + r, col = X0 + 64wv + m + 16t ----
    const float bv = bias[0];
    const int orow0 = R0 + quad * 4;
    const int ocol0 = X0 + 64 * wv + m;
    if ((ocol0 + 48 < OW) & (R0 + 15 < OW)) {
        float* o0 = &out[(size_t)orow0 * OW + ocol0];
        #pragma unroll
        for (int t = 0; t < 4; ++t) {
            #pragma unroll
            for (int r = 0; r < 4; ++r)
                o0[(size_t)r * OW + t * 16] = acc[t][r] + bv;
        }
    } else {
        #pragma unroll
        for (int t = 0; t < 4; ++t) {
            int oc = ocol0 + t * 16;
            if (oc < OW) {
                #pragma unroll
                for (int r = 0; r < 4; ++r) {
                    int orow = orow0 + r;
                    if (orow < OW)
                        out[(size_t)orow * OW + oc] = acc[t][r] + bv;
                }
            }
        }
    }
}

extern "C" void kernel_launch(void* const* d_in, const int* in_sizes, int n_in,
                              void* d_out, int out_size, void* d_ws, size_t ws_size,
                              hipStream_t stream) {
    const float* x    = (const float*)d_in[0];
    const float* w    = (const float*)d_in[1];
    const float* bias = (const float*)d_in[2];
    float* out        = (float*)d_out;
    unsigned short* Bg = (unsigned short*)d_ws;     // 15 KiB of scratch

    build_B<<<dim3(KS), dim3(64), 0, stream>>>(w, Bg);
    dim3 grid(NCG, NRT);
    conv2d_mfma6<<<grid, dim3(256), 0, stream>>>(x, Bg, bias, out);
}

// Round 5
// 140.933 us; speedup vs baseline: 1.3481x; 1.1821x over previous
//
#include <hip/hip_runtime.h>

#define IN_N   4096
#define OW     4084          // (4096 + 2*1 - 15) + 1
#define KS     15
#define TILE   64            // 64x64 output tile per block (4 waves x 16 rows)
#define XROWS  78            // TILE + KS - 1
#define XS     88            // LDS row stride in halfwords (176 B: 16B-mult)
#define NBX    64
#define NBY    64

typedef __attribute__((ext_vector_type(8))) short     v8s;   // raw 16B
typedef __attribute__((ext_vector_type(8))) _Float16  v8h;   // f16 A/B frag (4 VGPR)
typedef __attribute__((ext_vector_type(4))) float     v4f;   // C/D frag
typedef __attribute__((ext_vector_type(2))) float     v2f;
typedef __attribute__((ext_vector_type(2))) unsigned  v2u;

// ---- pre-kernel: build the 15 banded-B MFMA fragments once into d_ws ----
// B_ky[k][n] = w[ky, k-1-n] (band k ∈ [n+1, n+15]); A k-window starts at EVEN
// global col X0-2 -> aligned float2 staging.
// lane e holds B[k = (e>>4)*8 + j][n = e&15], j = 0..7  (16 B per lane)
__global__ void build_B(const float* __restrict__ w, unsigned short* __restrict__ Bg) {
    int ky = blockIdx.x;         // 15
    int e  = threadIdx.x;        // 64
    int n = e & 15, quad = e >> 4;
    unsigned short vals[8];
    #pragma unroll
    for (int j = 0; j < 8; ++j) {
        int d = quad * 8 + j - 1 - n;                 // shifted band
        _Float16 h = (_Float16)0.0f;
        if (d >= 0 && d < KS) h = (_Float16)w[ky * KS + d];   // RTNE f32->f16
        union { _Float16 hh; unsigned short u; } cv; cv.hh = h;
        vals[j] = cv.u;
    }
    *(v8s*)(&Bg[(ky * 64 + e) * 8]) = *(const v8s*)vals;
}

__device__ __forceinline__ unsigned pk(float a, float b) {
    return __builtin_bit_cast(unsigned, __builtin_amdgcn_cvt_pkrtz(a, b));
}

// R1 structure + full B operand hoisted to registers (60 VGPR) before staging.
// ky-loop is pure LDS reads + MFMA: no per-iteration VMEM latency exposure.
__global__ __launch_bounds__(256, 4) void conv2d_mfma7(
    const float* __restrict__ x, const unsigned short* __restrict__ Bg,
    const float* __restrict__ bias, float* __restrict__ out)
{
    __shared__ unsigned short xtile[XROWS * XS] __attribute__((aligned(16)));

    const int tid = threadIdx.x;
    const int bx = blockIdx.x, by = blockIdx.y;
    const int X0 = bx * TILE;
    const int Y0 = by * TILE;
    const bool interior = (bx > 0) & (bx < NBX - 1) & (by > 0) & (by < NBY - 1);

    const int lane = tid & 63;

    // ---- issue B preload FIRST: latency hides under the staging phase ----
    const v8h* Bgv = (const v8h*)Bg;
    v8h bfr[KS];
    #pragma unroll
    for (int ky = 0; ky < KS; ++ky) bfr[ky] = Bgv[ky * 64 + lane];

    // ---- stage input tile fp32 -> f16 ----
    // LDS (row, col) = global (Y0-1+row, X0-2+col), col in [0,80)
    // 240 threads as 12 rows x 20 four-col units; 7 row-sweeps cover 78 rows.
    if (tid < 240) {
        const int tcol = tid % 20;
        const int trow = tid / 20;                    // 0..11
        const int c0 = 4 * tcol;                      // halfword col, 8B-aligned
        unsigned short* dst = &xtile[trow * XS + c0];
        if (interior) {
            const float* xr = x + (size_t)(Y0 - 1 + trow) * IN_N + (X0 - 2 + c0);
            #pragma unroll
            for (int i = 0; i < 7; ++i) {
                if (i < 6 || trow < 6) {              // rows 72..77 on last sweep
                    v2f f01 = *(const v2f*)xr;        // aligned dwordx2
                    v2f f23 = *(const v2f*)(xr + 2);
                    v2u p;
                    p.x = pk(f01.x, f01.y);
                    p.y = pk(f23.x, f23.y);
                    *(v2u*)dst = p;                   // ds_write_b64
                }
                xr  += 12 * (size_t)IN_N;
                dst += 12 * XS;
            }
        } else {
            const int gc0 = X0 - 2 + c0;
            #pragma unroll
            for (int i = 0; i < 7; ++i) {
                int row = trow + 12 * i;
                if (row < XROWS) {
                    int gr = Y0 - 1 + row;
                    float f0 = 0.f, f1 = 0.f, f2 = 0.f, f3 = 0.f;
                    if ((unsigned)gr < (unsigned)IN_N) {
                        const float* xr = x + (size_t)gr * IN_N;
                        if ((unsigned)(gc0 + 0) < (unsigned)IN_N) f0 = xr[gc0 + 0];
                        if ((unsigned)(gc0 + 1) < (unsigned)IN_N) f1 = xr[gc0 + 1];
                        if ((unsigned)(gc0 + 2) < (unsigned)IN_N) f2 = xr[gc0 + 2];
                        if ((unsigned)(gc0 + 3) < (unsigned)IN_N) f3 = xr[gc0 + 3];
                    }
                    v2u p;
                    p.x = pk(f0, f1);
                    p.y = pk(f2, f3);
                    *(v2u*)(&xtile[row * XS + c0]) = p;
                }
            }
        }
    }
    __syncthreads();

    // ---- MFMA main loop: pure LDS + MFMA (B fully in registers) ----
    const int wv   = tid >> 6;
    const int m    = lane & 15;
    const int quad = lane >> 4;

    v4f acc[4];
    #pragma unroll
    for (int t = 0; t < 4; ++t) acc[t] = (v4f){0.f, 0.f, 0.f, 0.f};

    const unsigned short* arow = &xtile[(wv * 16 + m) * XS + quad * 8];

    #pragma unroll
    for (int ky = 0; ky < KS; ++ky) {
        v8h a0 = *(const v8h*)(arow + 0);             // ds_read_b128 x4
        v8h a1 = *(const v8h*)(arow + 16);
        v8h a2 = *(const v8h*)(arow + 32);
        v8h a3 = *(const v8h*)(arow + 48);
        acc[0] = __builtin_amdgcn_mfma_f32_16x16x32_f16(a0, bfr[ky], acc[0], 0, 0, 0);
        acc[1] = __builtin_amdgcn_mfma_f32_16x16x32_f16(a1, bfr[ky], acc[1], 0, 0, 0);
        acc[2] = __builtin_amdgcn_mfma_f32_16x16x32_f16(a2, bfr[ky], acc[2], 0, 0, 0);
        acc[3] = __builtin_amdgcn_mfma_f32_16x16x32_f16(a3, bfr[ky], acc[3], 0, 0, 0);
        arow += XS;
    }

    // ---- epilogue: D[m,n] -> out; row = quad*4 + r, col = m (+16t) ----
    const float bv = bias[0];
    const int orow0 = Y0 + wv * 16 + quad * 4;
    const int ocol0 = X0 + m;
    if (interior | ((bx < NBX - 1) & (by < NBY - 1))) {
        float* o0 = &out[(size_t)orow0 * OW + ocol0];
        #pragma unroll
        for (int t = 0; t < 4; ++t) {
            #pragma unroll
            for (int r = 0; r < 4; ++r)
                o0[(size_t)r * OW + t * 16] = acc[t][r] + bv;
        }
    } else {
        #pragma unroll
        for (int t = 0; t < 4; ++t) {
            int oc = ocol0 + t * 16;
            if (oc < OW) {
                #pragma unroll
                for (int r = 0; r < 4; ++r) {
                    int orow = orow0 + r;
                    if (orow < OW)
                        out[(size_t)orow * OW + oc] = acc[t][r] + bv;
                }
            }
        }
    }
}

extern "C" void kernel_launch(void* const* d_in, const int* in_sizes, int n_in,
                              void* d_out, int out_size, void* d_ws, size_t ws_size,
                              hipStream_t stream) {
    const float* x    = (const float*)d_in[0];
    const float* w    = (const float*)d_in[1];
    const float* bias = (const float*)d_in[2];
    float* out        = (float*)d_out;
    unsigned short* Bg = (unsigned short*)d_ws;     // 15 KiB of scratch

    build_B<<<dim3(KS), dim3(64), 0, stream>>>(w, Bg);
    dim3 grid(NBX, NBY);
    conv2d_mfma7<<<grid, dim3(256), 0, stream>>>(x, Bg, bias, out);
}